// Round 1
// baseline (986.564 us; speedup 1.0000x reference)
//
#include <hip/hip_runtime.h>

#define B_    8
#define V_    100000
#define FIN_  32
#define K_    4
#define FOUT_ 64
#define E_    800000
#define NODE_F 256   // B_ * FIN_ floats per node row

// ---------------- transpose: inputs [B][V][FIN] -> x0 [V][B][FIN] ----------
__global__ __launch_bounds__(256) void k_transpose(const float* __restrict__ in,
                                                   float* __restrict__ x0) {
    int tid = blockIdx.x * 256 + threadIdx.x;     // over V_*B_*8 float4s
    int f4 = tid & 7;
    int m  = tid >> 3;          // m = v*8 + b
    int v  = m >> 3;
    int b  = m & 7;
    const float4* src = (const float4*)(in + ((size_t)b * V_ + v) * FIN_);
    float4 val = src[f4];
    ((float4*)x0)[tid] = val;
}

// ---------------- CSR build ------------------------------------------------
__global__ __launch_bounds__(256) void k_zero_int(int* __restrict__ p, int n) {
    int t = blockIdx.x * 256 + threadIdx.x;
    if (t < n) p[t] = 0;
}

__global__ __launch_bounds__(256) void k_hist(const int* __restrict__ rows,
                                              int* __restrict__ counts) {
    int e = blockIdx.x * 256 + threadIdx.x;
    if (e < E_) atomicAdd(&counts[rows[e]], 1);
}

// exclusive scan of 1024-element chunks; writes per-block totals
__global__ __launch_bounds__(1024) void k_scan1(const int* __restrict__ counts,
                                                int* __restrict__ out,
                                                int* __restrict__ bsums, int n) {
    __shared__ int s[1024];
    int t = threadIdx.x;
    int idx = blockIdx.x * 1024 + t;
    int v = (idx < n) ? counts[idx] : 0;
    s[t] = v;
    __syncthreads();
    for (int off = 1; off < 1024; off <<= 1) {
        int add = (t >= off) ? s[t - off] : 0;
        __syncthreads();
        s[t] += add;
        __syncthreads();
    }
    if (idx < n) out[idx] = s[t] - v;   // exclusive
    if (t == 1023) bsums[blockIdx.x] = s[1023];
}

// exclusive scan of (<=128) block sums in one block
__global__ __launch_bounds__(128) void k_scan2(const int* __restrict__ bsums,
                                               int* __restrict__ boffs, int nb) {
    __shared__ int s[128];
    int t = threadIdx.x;
    int v = (t < nb) ? bsums[t] : 0;
    s[t] = v;
    __syncthreads();
    for (int off = 1; off < 128; off <<= 1) {
        int add = (t >= off) ? s[t - off] : 0;
        __syncthreads();
        s[t] += add;
        __syncthreads();
    }
    boffs[t] = s[t] - v;
}

__global__ __launch_bounds__(1024) void k_scan3(int* __restrict__ row_ptr,
                                                int* __restrict__ cursor,
                                                const int* __restrict__ boffs, int n) {
    int idx = blockIdx.x * 1024 + threadIdx.x;
    if (idx < n) {
        int r = row_ptr[idx] + boffs[blockIdx.x];
        row_ptr[idx] = r;
        cursor[idx]  = r;
    }
}

__global__ __launch_bounds__(256) void k_scatter(const int* __restrict__ rows,
                                                 const int* __restrict__ cols,
                                                 const float* __restrict__ vals,
                                                 int* __restrict__ cursor,
                                                 int* __restrict__ e_col,
                                                 float* __restrict__ e_val) {
    int e = blockIdx.x * 256 + threadIdx.x;
    if (e < E_) {
        int r = rows[e];
        int pos = atomicAdd(&cursor[r], 1);
        e_col[pos] = cols[e];
        e_val[pos] = vals[e];
    }
}

// ---------------- SpMM + Chebyshev recurrence ------------------------------
// xn[v] = scale * (L @ xc)[v] - (has_prev ? xp[v] : 0)
// one 64-lane wave per row; lane handles float4 (256 floats per node)
__global__ __launch_bounds__(256) void k_spmm(const float* __restrict__ xc,
                                              const float* __restrict__ xp,
                                              const int* __restrict__ row_ptr,
                                              const int* __restrict__ e_col,
                                              const float* __restrict__ e_val,
                                              float* __restrict__ xn,
                                              float scale, int has_prev) {
    int wave = threadIdx.x >> 6;
    int lane = threadIdx.x & 63;
    int v = blockIdx.x * 4 + wave;
    if (v >= V_) return;
    int beg = row_ptr[v];
    int end = (v == V_ - 1) ? E_ : row_ptr[v + 1];
    float4 acc = make_float4(0.f, 0.f, 0.f, 0.f);
    for (int e = beg; e < end; ++e) {
        int c = e_col[e];
        float val = e_val[e];
        float4 x = ((const float4*)(xc + (size_t)c * NODE_F))[lane];
        acc.x += val * x.x;
        acc.y += val * x.y;
        acc.z += val * x.z;
        acc.w += val * x.w;
    }
    float4 r;
    if (has_prev) {
        float4 p = ((const float4*)(xp + (size_t)v * NODE_F))[lane];
        r.x = scale * acc.x - p.x;
        r.y = scale * acc.y - p.y;
        r.z = scale * acc.z - p.z;
        r.w = scale * acc.w - p.w;
    } else {
        r = acc;
    }
    ((float4*)(xn + (size_t)v * NODE_F))[lane] = r;
}

// ---------------- contraction: out[b,v,o] = sum_{k,f} x_k[v,b,f] W[f,k,o] + bias[o]
// GEMM: M = V*B (row m = v*8+b), Kdim = 128 (4 chunks of 32), N = 64.
// Block: 64 rows x 64 cols, 256 threads, 4x4 micro-tile.
__global__ __launch_bounds__(256) void k_contract(const float* __restrict__ x0,
                                                  const float* __restrict__ x1,
                                                  const float* __restrict__ x2,
                                                  const float* __restrict__ x3,
                                                  const float* __restrict__ weight,
                                                  const float* __restrict__ bias,
                                                  float* __restrict__ out) {
    __shared__ float Ws[4 * 32 * 64];   // [k][f][o]
    __shared__ float At[32 * 68];       // [f][row], padded stride 68 (16B-aligned, conflict-free)
    int tid = threadIdx.x;

    // stage W: weight [f][k][o] flat -> Ws[k][f][o]
    for (int j = tid; j < 2048; j += 256) {
        float4 w = ((const float4*)weight)[j];
        int base = j * 4;            // flat idx = f*256 + k*64 + o
        int f = base >> 8;
        int k = (base >> 6) & 3;
        int o = base & 63;
        *((float4*)&Ws[(k * 32 + f) * 64 + o]) = w;
    }

    const float* xs[4] = {x0, x1, x2, x3};
    int m0 = blockIdx.x * 64;
    int ty = tid >> 4;   // row group 0..15
    int tx = tid & 15;   // col group 0..15
    float acc[4][4] = {};

    for (int k = 0; k < 4; ++k) {
        __syncthreads();
        // stage A chunk: 64 rows x 32 floats (contiguous), store transposed
        const float4* src = (const float4*)(xs[k] + (size_t)m0 * 32);
        for (int j = tid; j < 512; j += 256) {
            float4 a = src[j];
            int row = j >> 3;
            int f4  = j & 7;
            At[(f4 * 4 + 0) * 68 + row] = a.x;
            At[(f4 * 4 + 1) * 68 + row] = a.y;
            At[(f4 * 4 + 2) * 68 + row] = a.z;
            At[(f4 * 4 + 3) * 68 + row] = a.w;
        }
        __syncthreads();
        #pragma unroll
        for (int f = 0; f < 32; ++f) {
            float4 a4 = *((const float4*)&At[f * 68 + ty * 4]);
            float4 w4 = *((const float4*)&Ws[(k * 32 + f) * 64 + tx * 4]);
            float a[4] = {a4.x, a4.y, a4.z, a4.w};
            float w[4] = {w4.x, w4.y, w4.z, w4.w};
            #pragma unroll
            for (int i = 0; i < 4; ++i)
                #pragma unroll
                for (int jj = 0; jj < 4; ++jj)
                    acc[i][jj] += a[i] * w[jj];
        }
    }

    float4 bi = ((const float4*)bias)[tx];
    #pragma unroll
    for (int i = 0; i < 4; ++i) {
        int m = m0 + ty * 4 + i;
        int v = m >> 3;
        int b = m & 7;
        float4 r;
        r.x = acc[i][0] + bi.x;
        r.y = acc[i][1] + bi.y;
        r.z = acc[i][2] + bi.z;
        r.w = acc[i][3] + bi.w;
        ((float4*)(out + ((size_t)b * V_ + v) * FOUT_))[tx] = r;
    }
}

// ---------------- launcher -------------------------------------------------
extern "C" void kernel_launch(void* const* d_in, const int* in_sizes, int n_in,
                              void* d_out, int out_size, void* d_ws, size_t ws_size,
                              hipStream_t stream) {
    const float* inputs  = (const float*)d_in[0];
    const int*   laprows = (const int*)d_in[1];
    const int*   lapcols = (const int*)d_in[2];
    const float* lapvals = (const float*)d_in[3];
    const float* weight  = (const float*)d_in[4];
    const float* bias    = (const float*)d_in[5];
    float* out = (float*)d_out;

    const size_t XN = (size_t)V_ * NODE_F;   // 25.6M floats per buffer
    float* x0 = (float*)d_ws;
    float* x1 = x0 + XN;
    float* x2 = x1 + XN;
    float* x3 = x2 + XN;
    int* counts  = (int*)(x3 + XN);
    int* row_ptr = counts + V_;
    int* cursor  = row_ptr + V_;
    int* bsums   = cursor + V_;
    int* boffs   = bsums + 128;
    int* e_col   = boffs + 128;
    float* e_val = (float*)(e_col + E_);

    const int NB_SCAN = (V_ + 1023) / 1024;   // 98

    hipLaunchKernelGGL(k_zero_int, dim3((V_ + 255) / 256), dim3(256), 0, stream, counts, V_);
    hipLaunchKernelGGL(k_transpose, dim3((V_ * B_ * 8) / 256), dim3(256), 0, stream, inputs, x0);
    hipLaunchKernelGGL(k_hist, dim3((E_ + 255) / 256), dim3(256), 0, stream, laprows, counts);
    hipLaunchKernelGGL(k_scan1, dim3(NB_SCAN), dim3(1024), 0, stream, counts, row_ptr, bsums, V_);
    hipLaunchKernelGGL(k_scan2, dim3(1), dim3(128), 0, stream, bsums, boffs, NB_SCAN);
    hipLaunchKernelGGL(k_scan3, dim3(NB_SCAN), dim3(1024), 0, stream, row_ptr, cursor, boffs, V_);
    hipLaunchKernelGGL(k_scatter, dim3((E_ + 255) / 256), dim3(256), 0, stream,
                       laprows, lapcols, lapvals, cursor, e_col, e_val);

    // x1 = L x0 ; x2 = 2 L x1 - x0 ; x3 = 2 L x2 - x1
    hipLaunchKernelGGL(k_spmm, dim3(V_ / 4), dim3(256), 0, stream,
                       x0, (const float*)nullptr, row_ptr, e_col, e_val, x1, 1.0f, 0);
    hipLaunchKernelGGL(k_spmm, dim3(V_ / 4), dim3(256), 0, stream,
                       x1, x0, row_ptr, e_col, e_val, x2, 2.0f, 1);
    hipLaunchKernelGGL(k_spmm, dim3(V_ / 4), dim3(256), 0, stream,
                       x2, x1, row_ptr, e_col, e_val, x3, 2.0f, 1);

    hipLaunchKernelGGL(k_contract, dim3(V_ * B_ / 64), dim3(256), 0, stream,
                       x0, x1, x2, x3, weight, bias, out);
}

// Round 3
// 757.207 us; speedup vs baseline: 1.3029x; 1.3029x over previous
//
#include <hip/hip_runtime.h>
#include <hip/hip_bf16.h>

#define B_    8
#define V_    100000
#define FIN_  32
#define K_    4
#define FOUT_ 64
#define E_    800000
#define NODE_F 256   // B_ * FIN_ elements per node row

typedef __attribute__((ext_vector_type(8))) short bf16x8;
typedef __attribute__((ext_vector_type(4))) float floatx4;

static __device__ inline float bf2f(unsigned short u) {
    unsigned int x = ((unsigned int)u) << 16;
    return __builtin_bit_cast(float, x);
}
static __device__ inline unsigned short f2bf(float f) {
    __hip_bfloat16 h = __float2bfloat16(f);   // RNE
    return __builtin_bit_cast(unsigned short, h);
}

// ---------------- transpose: inputs [B][V][FIN] fp32 -> x0 [V][B][FIN] bf16
__global__ __launch_bounds__(256) void k_transpose(const float* __restrict__ in,
                                                   unsigned short* __restrict__ x0) {
    int tid = blockIdx.x * 256 + threadIdx.x;     // over V_*B_*8 groups of 4
    int f4 = tid & 7;
    int m  = tid >> 3;          // m = v*8 + b
    int v  = m >> 3;
    int b  = m & 7;
    float4 val = ((const float4*)(in + ((size_t)b * V_ + v) * FIN_))[f4];
    ushort4 o;
    o.x = f2bf(val.x); o.y = f2bf(val.y); o.z = f2bf(val.z); o.w = f2bf(val.w);
    ((ushort4*)x0)[tid] = o;
}

// ---------------- CSR build ------------------------------------------------
__global__ __launch_bounds__(256) void k_zero_int(int* __restrict__ p, int n) {
    int t = blockIdx.x * 256 + threadIdx.x;
    if (t < n) p[t] = 0;
}

__global__ __launch_bounds__(256) void k_hist(const int* __restrict__ rows,
                                              int* __restrict__ counts) {
    int e = blockIdx.x * 256 + threadIdx.x;
    if (e < E_) atomicAdd(&counts[rows[e]], 1);
}

__global__ __launch_bounds__(1024) void k_scan1(const int* __restrict__ counts,
                                                int* __restrict__ out,
                                                int* __restrict__ bsums, int n) {
    __shared__ int s[1024];
    int t = threadIdx.x;
    int idx = blockIdx.x * 1024 + t;
    int v = (idx < n) ? counts[idx] : 0;
    s[t] = v;
    __syncthreads();
    for (int off = 1; off < 1024; off <<= 1) {
        int add = (t >= off) ? s[t - off] : 0;
        __syncthreads();
        s[t] += add;
        __syncthreads();
    }
    if (idx < n) out[idx] = s[t] - v;   // exclusive
    if (t == 1023) bsums[blockIdx.x] = s[1023];
}

__global__ __launch_bounds__(128) void k_scan2(const int* __restrict__ bsums,
                                               int* __restrict__ boffs, int nb) {
    __shared__ int s[128];
    int t = threadIdx.x;
    int v = (t < nb) ? bsums[t] : 0;
    s[t] = v;
    __syncthreads();
    for (int off = 1; off < 128; off <<= 1) {
        int add = (t >= off) ? s[t - off] : 0;
        __syncthreads();
        s[t] += add;
        __syncthreads();
    }
    boffs[t] = s[t] - v;
}

__global__ __launch_bounds__(1024) void k_scan3(int* __restrict__ row_ptr,
                                                int* __restrict__ cursor,
                                                const int* __restrict__ boffs, int n) {
    int idx = blockIdx.x * 1024 + threadIdx.x;
    if (idx < n) {
        int r = row_ptr[idx] + boffs[blockIdx.x];
        row_ptr[idx] = r;
        cursor[idx]  = r;
    }
}

__global__ __launch_bounds__(256) void k_scatter(const int* __restrict__ rows,
                                                 const int* __restrict__ cols,
                                                 const float* __restrict__ vals,
                                                 int* __restrict__ cursor,
                                                 int* __restrict__ e_col,
                                                 float* __restrict__ e_val) {
    int e = blockIdx.x * 256 + threadIdx.x;
    if (e < E_) {
        int r = rows[e];
        int pos = atomicAdd(&cursor[r], 1);
        e_col[pos] = cols[e];
        e_val[pos] = vals[e];
    }
}

// ---------------- SpMM + Chebyshev recurrence (bf16 storage, fp32 accum) ---
// xn[v] = scale * (L @ xc)[v] - (has_prev ? xp[v] : 0)
__global__ __launch_bounds__(256) void k_spmm(const unsigned short* __restrict__ xc,
                                              const unsigned short* __restrict__ xp,
                                              const int* __restrict__ row_ptr,
                                              const int* __restrict__ e_col,
                                              const float* __restrict__ e_val,
                                              unsigned short* __restrict__ xn,
                                              float scale, int has_prev) {
    int wave = threadIdx.x >> 6;
    int lane = threadIdx.x & 63;
    int v = blockIdx.x * 4 + wave;
    if (v >= V_) return;
    int beg = row_ptr[v];
    int end = (v == V_ - 1) ? E_ : row_ptr[v + 1];
    float4 acc = make_float4(0.f, 0.f, 0.f, 0.f);
    for (int e = beg; e < end; ++e) {
        int c = e_col[e];
        float val = e_val[e];
        ushort4 x = ((const ushort4*)(xc + (size_t)c * NODE_F))[lane];
        acc.x += val * bf2f(x.x);
        acc.y += val * bf2f(x.y);
        acc.z += val * bf2f(x.z);
        acc.w += val * bf2f(x.w);
    }
    float4 r;
    if (has_prev) {
        ushort4 p = ((const ushort4*)(xp + (size_t)v * NODE_F))[lane];
        r.x = scale * acc.x - bf2f(p.x);
        r.y = scale * acc.y - bf2f(p.y);
        r.z = scale * acc.z - bf2f(p.z);
        r.w = scale * acc.w - bf2f(p.w);
    } else {
        r = acc;
    }
    ushort4 o;
    o.x = f2bf(r.x); o.y = f2bf(r.y); o.z = f2bf(r.z); o.w = f2bf(r.w);
    ((ushort4*)(xn + (size_t)v * NODE_F))[lane] = o;
}

// ---------------- contraction via MFMA -------------------------------------
// out[b,v,o] = sum_{k,f} x_k[v,b,f] W[f,k,o] + bias[o]
// GEMM: M = V*B (row m = v*8+b), Kdim = 128 (4 chunks of 32), N = 64.
// One wave per 16-row m-tile x full N=64. B-frags (W) in registers, no LDS.
// mfma_f32_16x16x32_bf16: A[m=lane&15][k=quad*8+j]; B[k=quad*8+j][n=lane&15];
// D: col=lane&15, row=quad*4+reg.
__global__ __launch_bounds__(256) void k_contract(const unsigned short* __restrict__ x0,
                                                  const unsigned short* __restrict__ x1,
                                                  const unsigned short* __restrict__ x2,
                                                  const unsigned short* __restrict__ x3,
                                                  const float* __restrict__ weight,
                                                  const float* __restrict__ bias,
                                                  float* __restrict__ out) {
    int wave = threadIdx.x >> 6;
    int lane = threadIdx.x & 63;
    int quad = lane >> 4;
    int l16  = lane & 15;
    const unsigned short* xs[4] = {x0, x1, x2, x3};

    // B fragments: weight[f][k][o], chunk kq -> W[:,kq,:] [32f x 64o]
    bf16x8 bfrag[4][4];
    #pragma unroll
    for (int kq = 0; kq < 4; ++kq) {
        #pragma unroll
        for (int nt = 0; nt < 4; ++nt) {
            bf16x8 bf;
            #pragma unroll
            for (int j = 0; j < 8; ++j) {
                int f = quad * 8 + j;
                int o = nt * 16 + l16;
                bf[j] = (short)f2bf(weight[(size_t)f * (K_ * FOUT_) + kq * FOUT_ + o]);
            }
            bfrag[kq][nt] = bf;
        }
    }
    float bi[4];
    #pragma unroll
    for (int nt = 0; nt < 4; ++nt) bi[nt] = bias[nt * 16 + l16];

    int mt = blockIdx.x * 4 + wave;      // m-tile index (16 rows each)
    int m0 = mt * 16;

    floatx4 acc[4] = {{0,0,0,0},{0,0,0,0},{0,0,0,0},{0,0,0,0}};
    #pragma unroll
    for (int kq = 0; kq < 4; ++kq) {
        bf16x8 a = *((const bf16x8*)(xs[kq] + ((size_t)(m0 + l16)) * FIN_ + quad * 8));
        #pragma unroll
        for (int nt = 0; nt < 4; ++nt)
            acc[nt] = __builtin_amdgcn_mfma_f32_16x16x32_bf16(a, bfrag[kq][nt], acc[nt], 0, 0, 0);
    }

    #pragma unroll
    for (int nt = 0; nt < 4; ++nt) {
        int o = nt * 16 + l16;
        #pragma unroll
        for (int r = 0; r < 4; ++r) {
            int m = m0 + quad * 4 + r;
            int v = m >> 3;
            int b = m & 7;
            out[((size_t)b * V_ + v) * FOUT_ + o] = acc[nt][r] + bi[nt];
        }
    }
}

// ---------------- launcher -------------------------------------------------
extern "C" void kernel_launch(void* const* d_in, const int* in_sizes, int n_in,
                              void* d_out, int out_size, void* d_ws, size_t ws_size,
                              hipStream_t stream) {
    const float* inputs  = (const float*)d_in[0];
    const int*   laprows = (const int*)d_in[1];
    const int*   lapcols = (const int*)d_in[2];
    const float* lapvals = (const float*)d_in[3];
    const float* weight  = (const float*)d_in[4];
    const float* bias    = (const float*)d_in[5];
    float* out = (float*)d_out;

    const size_t XN = (size_t)V_ * NODE_F;   // 25.6M bf16 per buffer
    unsigned short* x0 = (unsigned short*)d_ws;
    unsigned short* x1 = x0 + XN;
    unsigned short* x2 = x1 + XN;
    unsigned short* x3 = x2 + XN;
    int* counts  = (int*)(x3 + XN);
    int* row_ptr = counts + V_;
    int* cursor  = row_ptr + V_;
    int* bsums   = cursor + V_;
    int* boffs   = bsums + 128;
    int* e_col   = boffs + 128;
    float* e_val = (float*)(e_col + E_);

    const int NB_SCAN = (V_ + 1023) / 1024;   // 98

    hipLaunchKernelGGL(k_zero_int, dim3((V_ + 255) / 256), dim3(256), 0, stream, counts, V_);
    hipLaunchKernelGGL(k_transpose, dim3((V_ * B_ * 8) / 256), dim3(256), 0, stream, inputs, x0);
    hipLaunchKernelGGL(k_hist, dim3((E_ + 255) / 256), dim3(256), 0, stream, laprows, counts);
    hipLaunchKernelGGL(k_scan1, dim3(NB_SCAN), dim3(1024), 0, stream, counts, row_ptr, bsums, V_);
    hipLaunchKernelGGL(k_scan2, dim3(1), dim3(128), 0, stream, bsums, boffs, NB_SCAN);
    hipLaunchKernelGGL(k_scan3, dim3(NB_SCAN), dim3(1024), 0, stream, row_ptr, cursor, boffs, V_);
    hipLaunchKernelGGL(k_scatter, dim3((E_ + 255) / 256), dim3(256), 0, stream,
                       laprows, lapcols, lapvals, cursor, e_col, e_val);

    // x1 = L x0 ; x2 = 2 L x1 - x0 ; x3 = 2 L x2 - x1
    hipLaunchKernelGGL(k_spmm, dim3(V_ / 4), dim3(256), 0, stream,
                       x0, (const unsigned short*)nullptr, row_ptr, e_col, e_val, x1, 1.0f, 0);
    hipLaunchKernelGGL(k_spmm, dim3(V_ / 4), dim3(256), 0, stream,
                       x1, x0, row_ptr, e_col, e_val, x2, 2.0f, 1);
    hipLaunchKernelGGL(k_spmm, dim3(V_ / 4), dim3(256), 0, stream,
                       x2, x1, row_ptr, e_col, e_val, x3, 2.0f, 1);

    // grid: M / (waves_per_block * 16 rows) = 800000 / 64 = 12500
    hipLaunchKernelGGL(k_contract, dim3(V_ * B_ / 64), dim3(256), 0, stream,
                       x0, x1, x2, x3, weight, bias, out);
}